// Round 1
// baseline (106.570 us; speedup 1.0000x reference)
//
#include <hip/hip_runtime.h>

// Problem constants (from reference):
//   x:       (B=4, R=256, H=32, W=32) fp32  -> flat (b*256 + r)*1024 + l, l = h*32+w
//   indexes: (B*1024,) int                  -> weight/bias selector in [0,8)
//   weight:  (8, 256, 256) fp32             -> (j*256 + r)*256 + c
//   bias:    (8, 256) fp32                  -> j*256 + c
//   out:     (B, 256, 32, 32) fp32          -> (b*256 + c)*1024 + l
//
// out[b,c,l] = sum_r x[b,r,l] * weight[idx[b,l], r, c] + bias[idx[b,l], c]

#define L_DIM 1024
#define R_MAX 256
#define C_DIM 256

__global__ __launch_bounds__(256) void rate_adaption_decoder_kernel(
    const float* __restrict__ x,
    const int*   __restrict__ indexes,
    const float* __restrict__ weight,
    const float* __restrict__ bias,
    float*       __restrict__ out)
{
    __shared__ float xs[R_MAX];

    const int tok = blockIdx.x;          // b*1024 + l
    const int b   = tok >> 10;
    const int l   = tok & 1023;
    const int c   = threadIdx.x;         // one output channel per thread

    // Stage this token's x-vector (256 floats) into LDS.
    // Thread t loads x[b, t, l] (stride-1024 gather; L2 absorbs — each
    // element is read exactly once across the whole grid).
    xs[c] = x[((b << 8) + c) * L_DIM + l];
    __syncthreads();

    const int j = indexes[tok];

    // Coalesced weight reads: consecutive threads -> consecutive c.
    const float* __restrict__ wp = weight + j * (R_MAX * C_DIM) + c;

    float acc = bias[j * C_DIM + c];
    #pragma unroll 8
    for (int r = 0; r < R_MAX; ++r) {
        acc += xs[r] * wp[r * C_DIM];    // xs[r] is a wave-uniform LDS broadcast (free)
    }

    out[((b << 8) + c) * L_DIM + l] = acc;
}

extern "C" void kernel_launch(void* const* d_in, const int* in_sizes, int n_in,
                              void* d_out, int out_size, void* d_ws, size_t ws_size,
                              hipStream_t stream)
{
    const float* x      = (const float*)d_in[0];
    const int*   idx    = (const int*)  d_in[1];
    const float* weight = (const float*)d_in[2];
    const float* bias   = (const float*)d_in[3];
    float*       out    = (float*)      d_out;

    const int n_tok = in_sizes[1];       // B*H*W = 4096

    rate_adaption_decoder_kernel<<<n_tok, 256, 0, stream>>>(x, idx, weight, bias, out);
}